// Round 3
// baseline (5575.132 us; speedup 1.0000x reference)
//
#include <hip/hip_runtime.h>
#include <hip/hip_bf16.h>

// SparseBottleneck, output-stationary v2.
// v1 (round 2) was latency-bound: ~2 cache lines in flight per CU (serial
// pairs->gather->W-reload chain, 32KB of W re-read per chunk from L1).
// v2: per output tile, walk the 27 taps (bins) in order; W_k staged ONCE per
// bin into LDS (global_load_lds, double-buffered, pre-swizzled in global so
// linear staging lands conflict-free); A gathered per-lane into regs;
// lacc stride 144 (ds_add ~2-way); 16 waves/block, quarter-chunk tasks.

typedef __attribute__((ext_vector_type(8))) short short8;
typedef __attribute__((ext_vector_type(4))) float f32x4;

#define CDIM 128
#define BM   128
#define KTAPS 27
#define LSTRIDE 144
#define NEG_SLOPE 0.2f

#define GLOAD_LDS16(g, l) __builtin_amdgcn_global_load_lds(                 \
    (const __attribute__((address_space(1))) void*)(g),                     \
    (__attribute__((address_space(3))) void*)(l), 16, 0, 0)

__device__ __forceinline__ unsigned short f2bf(float x) {
    union { float f; unsigned u; } un; un.f = x;
    unsigned r = un.u + 0x7fffu + ((un.u >> 16) & 1u);   // RNE
    return (unsigned short)(r >> 16);
}

__device__ __forceinline__ float lrelu(float x) {
    return x >= 0.f ? x : NEG_SLOPE * x;
}

// swizzled LDS element index for conv2's staging (proven earlier)
__device__ __forceinline__ int swz(int r, int c) {
    return (r << 7) + ((((c >> 3) ^ (r & 15)) << 3));
}

// ---------------------------------------------------------------- converters
__global__ void cvt_feats_kernel(const float* __restrict__ in,
                                 unsigned short* __restrict__ out, int n4) {
    int i = blockIdx.x * blockDim.x + threadIdx.x;
    if (i >= n4) return;
    float4 v = reinterpret_cast<const float4*>(in)[i];
    ushort4 o;
    o.x = f2bf(v.x); o.y = f2bf(v.y); o.z = f2bf(v.z); o.w = f2bf(v.w);
    reinterpret_cast<ushort4*>(out)[i] = o;
}

// W1/W3: [K][Cin][Cout] -> Wt[K][Cout][Cin] bf16, row-swizzled:
//   Wt[k][n][kk ^ ((n&7)<<3)] = W[k][kk][n]
// so that a LINEAR global_load_lds staging lands XOR-swizzled in LDS and
// ds_read_b128 of B-fragments is ~2-way-conflict (free).
// W2: [Cin][Cout] -> W2t[Cout][Cin] (unswizzled; conv2 uses its own layout)
__global__ void cvt_weights_kernel(const float* __restrict__ W1,
                                   const float* __restrict__ W2,
                                   const float* __restrict__ W3,
                                   unsigned short* __restrict__ W1t,
                                   unsigned short* __restrict__ W2t,
                                   unsigned short* __restrict__ W3t) {
    const int KW = KTAPS * 128 * 128;                 // 442368
    int t = blockIdx.x * blockDim.x + threadIdx.x;
    if (t < KW) {
        int k = t >> 14, r = t & 16383, n = r >> 7, kk = r & 127;
        int kks = kk ^ ((n & 7) << 3);
        W1t[(k << 14) + (n << 7) + kks] = f2bf(W1[(k << 14) + (kk << 7) + n]);
    } else if (t < 2 * KW) {
        int t2 = t - KW;
        int k = t2 >> 14, r = t2 & 16383, n = r >> 7, kk = r & 127;
        int kks = kk ^ ((n & 7) << 3);
        W3t[(k << 14) + (n << 7) + kks] = f2bf(W3[(k << 14) + (kk << 7) + n]);
    } else if (t < 2 * KW + 16384) {
        int t2 = t - 2 * KW;
        int n = t2 >> 7, kk = t2 & 127;
        W2t[t2] = f2bf(W2[(kk << 7) + n]);
    }
}

// ---------------------------------------------------------------- binning prep
// bin = (out_row >> 7) * 27 + k ; runs once, reused by conv1 AND conv3.
__global__ void hist_kernel(const int* __restrict__ out_map,
                            int* __restrict__ cnt, int M) {
    int m = blockIdx.x * 256 + threadIdx.x;
    if (m >= M) return;
    int k = blockIdx.y;
    int orow = out_map[(size_t)k * M + m];
    atomicAdd(cnt + ((orow >> 7) * KTAPS + k), 1);
}

__global__ void scan_a_kernel(const int* __restrict__ cnt, int* __restrict__ cs,
                              int* __restrict__ partials, int NB) {
    __shared__ int sd[256];
    int tid = threadIdx.x, bin = blockIdx.x * 256 + tid;
    int v = (bin < NB) ? ((cnt[bin] + 15) >> 4) : 0;
    sd[tid] = v; __syncthreads();
    for (int off = 1; off < 256; off <<= 1) {
        int t = (tid >= off) ? sd[tid - off] : 0; __syncthreads();
        sd[tid] += t; __syncthreads();
    }
    if (bin < NB) cs[bin] = sd[tid] - v;      // block-local exclusive
    if (tid == 255) partials[blockIdx.x] = sd[255];
}

__global__ void scan_b_kernel(int* __restrict__ partials, int NBb) {
    __shared__ int sd[256];
    int tid = threadIdx.x;
    int v = (tid < NBb) ? partials[tid] : 0;
    sd[tid] = v; __syncthreads();
    for (int off = 1; off < 256; off <<= 1) {
        int t = (tid >= off) ? sd[tid - off] : 0; __syncthreads();
        sd[tid] += t; __syncthreads();
    }
    partials[tid] = sd[tid] - v;              // exclusive; partials[NBb] = total
}

__global__ void scan_c_kernel(int* __restrict__ cs, const int* __restrict__ partials,
                              int NB, int NBb) {
    int bin = blockIdx.x * 256 + threadIdx.x;
    if (bin < NB) cs[bin] += partials[blockIdx.x];
    if (bin == 0) cs[NB] = partials[NBb];
}

__global__ void fill_kernel(int* __restrict__ p, int n, int v) {
    int i = blockIdx.x * 256 + threadIdx.x;
    if (i < n) p[i] = v;
}

// entry pack: (k<<26) | (in_row<<8) | (out_row & 127)
__global__ void scatter_kernel(const int* __restrict__ in_map,
                               const int* __restrict__ out_map,
                               const int* __restrict__ cs,
                               int* __restrict__ cursor,
                               int* __restrict__ pairs, int M) {
    int m = blockIdx.x * 256 + threadIdx.x;
    if (m >= M) return;
    int k = blockIdx.y;
    size_t e = (size_t)k * M + m;
    int orow = out_map[e], irow = in_map[e];
    int bin = (orow >> 7) * KTAPS + k;
    int pos = atomicAdd(cursor + bin, 1);
    pairs[(size_t)cs[bin] * 16 + pos] = (k << 26) | (irow << 8) | (orow & 127);
}

// ---------------------------------------------------------------- fused sconv
// 1024 threads (16 waves), 1 block/CU (139 KB LDS). Per tile: 27 bins (k in
// order); W_k double-buffered in LDS; per bin, tasks = chunk x 2 j-tiles,
// wave w takes tasks w, w+16, ... Dummy entries: irow=N (zero row), srow=0.
template<int MODE>
__global__ __launch_bounds__(1024, 1)
void conv_fused_kernel(const unsigned short* __restrict__ A,    // [N+1,128] bf16, row N = 0
                       const unsigned short* __restrict__ Wt,   // [27][128][128] pre-swizzled
                       const int* __restrict__ pairs,
                       const int* __restrict__ cs,              // [NB+1] chunk starts
                       unsigned short* __restrict__ bf_out,     // MODE 0
                       float* __restrict__ f_out,               // MODE 1
                       const float* __restrict__ mask,
                       int N) {
    __shared__ float lacc[128 * LSTRIDE];            // 73.7 KB
    __shared__ unsigned short lW[2][128 * 128];      // 64 KB
    __shared__ int lcs[KTAPS + 1];

    const int tid  = threadIdx.x;
    const int tile = blockIdx.x;
    const int wid  = tid >> 6, lane = tid & 63;
    const int lrow = lane & 15, quad = lane >> 4;

    for (int i = tid; i < 128 * LSTRIDE / 4; i += 1024)
        reinterpret_cast<f32x4*>(lacc)[i] = (f32x4){0.f, 0.f, 0.f, 0.f};
    if (tid <= KTAPS) lcs[tid] = cs[tile * KTAPS + tid];

    // stage W for bin 0: wave w covers shorts [w*1024, w*1024+1024), 2 instrs
    {
        const unsigned short* g = Wt + wid * 1024 + lane * 8;
        unsigned short* l = &lW[0][wid * 1024];
        GLOAD_LDS16(g, l);
        GLOAD_LDS16(g + 512, l + 512);
    }
    asm volatile("s_waitcnt vmcnt(0)" ::: "memory");
    __syncthreads();

    for (int b = 0; b < KTAPS; ++b) {
        const int cur = b & 1;
        const int lo  = lcs[b];
        const int nt4 = (lcs[b + 1] - lo) << 2;

        int t = wid;
        const bool has0 = (t < nt4);        // wave-uniform
        int srow = 0, jj0 = 0;
        short8 a0 = {0,0,0,0,0,0,0,0}, a1 = a0, a2 = a0, a3 = a0;
        if (has0) {
            const int c = lo + (t >> 2);
            jj0 = (t & 3) << 1;
            int pk = pairs[c * 16 + lrow];
            int irow = (pk >> 8) & 0x3FFFF;
            srow = pk & 127;
            const unsigned short* ar = A + ((size_t)irow << 7) + quad * 8;
            a0 = *reinterpret_cast<const short8*>(ar);
            a1 = *reinterpret_cast<const short8*>(ar + 32);
            a2 = *reinterpret_cast<const short8*>(ar + 64);
            a3 = *reinterpret_cast<const short8*>(ar + 96);
        }
        // issue next-bin W staging AFTER first-task loads (vmcnt drains in
        // issue order; this keeps the A-wait from draining the stage)
        __builtin_amdgcn_sched_barrier(0);
        if (b + 1 < KTAPS) {
            const unsigned short* g = Wt + ((size_t)(b + 1) << 14) + wid * 1024 + lane * 8;
            unsigned short* l = &lW[cur ^ 1][wid * 1024];
            GLOAD_LDS16(g, l);
            GLOAD_LDS16(g + 512, l + 512);
        }
        __builtin_amdgcn_sched_barrier(0);

        if (has0) {
            // ---- compute first task
            {
                int sr0 = __shfl(srow, quad * 4 + 0);
                int sr1 = __shfl(srow, quad * 4 + 1);
                int sr2 = __shfl(srow, quad * 4 + 2);
                int sr3 = __shfl(srow, quad * 4 + 3);
                #pragma unroll
                for (int jj = jj0; jj < jj0 + 2; ++jj) {
                    const int row0 = jj * 16 + lrow;
                    const int sx = (row0 & 7) << 3;
                    const unsigned short* wb = &lW[cur][row0 << 7];
                    short8 b0 = *reinterpret_cast<const short8*>(wb + ((quad * 8 +  0) ^ sx));
                    short8 b1 = *reinterpret_cast<const short8*>(wb + ((quad * 8 + 32) ^ sx));
                    short8 b2 = *reinterpret_cast<const short8*>(wb + ((quad * 8 + 64) ^ sx));
                    short8 b3 = *reinterpret_cast<const short8*>(wb + ((quad * 8 + 96) ^ sx));
                    f32x4 acc = {0.f, 0.f, 0.f, 0.f};
                    acc = __builtin_amdgcn_mfma_f32_16x16x32_bf16(a0, b0, acc, 0, 0, 0);
                    acc = __builtin_amdgcn_mfma_f32_16x16x32_bf16(a1, b1, acc, 0, 0, 0);
                    acc = __builtin_amdgcn_mfma_f32_16x16x32_bf16(a2, b2, acc, 0, 0, 0);
                    acc = __builtin_amdgcn_mfma_f32_16x16x32_bf16(a3, b3, acc, 0, 0, 0);
                    float* colp = lacc + jj * 16 + lrow;
                    __hip_atomic_fetch_add(colp + sr0 * LSTRIDE, acc[0], __ATOMIC_RELAXED, __HIP_MEMORY_SCOPE_WORKGROUP);
                    __hip_atomic_fetch_add(colp + sr1 * LSTRIDE, acc[1], __ATOMIC_RELAXED, __HIP_MEMORY_SCOPE_WORKGROUP);
                    __hip_atomic_fetch_add(colp + sr2 * LSTRIDE, acc[2], __ATOMIC_RELAXED, __HIP_MEMORY_SCOPE_WORKGROUP);
                    __hip_atomic_fetch_add(colp + sr3 * LSTRIDE, acc[3], __ATOMIC_RELAXED, __HIP_MEMORY_SCOPE_WORKGROUP);
                }
            }
            // ---- remaining tasks (rare: ~1.1 tasks/wave/bin on average)
            for (t += 16; t < nt4; t += 16) {
                const int c = lo + (t >> 2);
                const int j0 = (t & 3) << 1;
                int pk = pairs[c * 16 + lrow];
                int irow = (pk >> 8) & 0x3FFFF;
                int sr = pk & 127;
                const unsigned short* ar = A + ((size_t)irow << 7) + quad * 8;
                short8 c0 = *reinterpret_cast<const short8*>(ar);
                short8 c1 = *reinterpret_cast<const short8*>(ar + 32);
                short8 c2 = *reinterpret_cast<const short8*>(ar + 64);
                short8 c3 = *reinterpret_cast<const short8*>(ar + 96);
                int sr0 = __shfl(sr, quad * 4 + 0);
                int sr1 = __shfl(sr, quad * 4 + 1);
                int sr2 = __shfl(sr, quad * 4 + 2);
                int sr3 = __shfl(sr, quad * 4 + 3);
                #pragma unroll
                for (int jj = j0; jj < j0 + 2; ++jj) {
                    const int row0 = jj * 16 + lrow;
                    const int sx = (row0 & 7) << 3;
                    const unsigned short* wb = &lW[cur][row0 << 7];
                    short8 b0 = *reinterpret_cast<const short8*>(wb + ((quad * 8 +  0) ^ sx));
                    short8 b1 = *reinterpret_cast<const short8*>(wb + ((quad * 8 + 32) ^ sx));
                    short8 b2 = *reinterpret_cast<const short8*>(wb + ((quad * 8 + 64) ^ sx));
                    short8 b3 = *reinterpret_cast<const short8*>(wb + ((quad * 8 + 96) ^ sx));
                    f32x4 acc = {0.f, 0.f, 0.f, 0.f};
                    acc = __builtin_amdgcn_mfma_f32_16x16x32_bf16(c0, b0, acc, 0, 0, 0);
                    acc = __builtin_amdgcn_mfma_f32_16x16x32_bf16(c1, b1, acc, 0, 0, 0);
                    acc = __builtin_amdgcn_mfma_f32_16x16x32_bf16(c2, b2, acc, 0, 0, 0);
                    acc = __builtin_amdgcn_mfma_f32_16x16x32_bf16(c3, b3, acc, 0, 0, 0);
                    float* colp = lacc + jj * 16 + lrow;
                    __hip_atomic_fetch_add(colp + sr0 * LSTRIDE, acc[0], __ATOMIC_RELAXED, __HIP_MEMORY_SCOPE_WORKGROUP);
                    __hip_atomic_fetch_add(colp + sr1 * LSTRIDE, acc[1], __ATOMIC_RELAXED, __HIP_MEMORY_SCOPE_WORKGROUP);
                    __hip_atomic_fetch_add(colp + sr2 * LSTRIDE, acc[2], __ATOMIC_RELAXED, __HIP_MEMORY_SCOPE_WORKGROUP);
                    __hip_atomic_fetch_add(colp + sr3 * LSTRIDE, acc[3], __ATOMIC_RELAXED, __HIP_MEMORY_SCOPE_WORKGROUP);
                }
            }
        }
        // drain this wave's staging loads, then block-wide barrier: next bin
        // reads lW[cur^1]; bin b+1 stages into lW[cur] (all readers done).
        asm volatile("s_waitcnt vmcnt(0)" ::: "memory");
        __syncthreads();
    }

    // epilogue: each output row written exactly once, coalesced
    const int gbase = tile << 7;
    #pragma unroll
    for (int it = 0; it < 4; ++it) {
        int flat = it * 1024 + tid;                // 4096 = 128 rows * 32 f4
        int r = flat >> 5, c4 = flat & 31;
        int g = gbase + r;
        if (g < N) {
            f32x4 v = *reinterpret_cast<f32x4*>(&lacc[r * LSTRIDE + c4 * 4]);
            if (MODE == 0) {
                ushort4 o;
                o.x = f2bf(lrelu(v[0])); o.y = f2bf(lrelu(v[1]));
                o.z = f2bf(lrelu(v[2])); o.w = f2bf(lrelu(v[3]));
                *reinterpret_cast<ushort4*>(bf_out + (size_t)g * CDIM + c4 * 4) = o;
            } else {
                float mv = mask[g];
                f32x4 o = {v[0] * mv, v[1] * mv, v[2] * mv, v[3] * mv};
                *reinterpret_cast<f32x4*>(f_out + (size_t)g * CDIM + c4 * 4) = o;
            }
        }
    }
}

// ---------------------------------------------------------------- dense conv2
// c2 = bf16(lrelu( c1 @ W2 ))  -- c1 already lrelu'd bf16 (written by conv1)
__global__ __launch_bounds__(256, 2)
void conv2_kernel(const unsigned short* __restrict__ c1,      // [N,128] bf16
                  const unsigned short* __restrict__ W2t,     // [128,128] bf16 [n][kk]
                  unsigned short* __restrict__ c2,            // [N,128] bf16
                  int N) {
    const int mbase = blockIdx.x * BM;
    const int tid   = threadIdx.x;

    __shared__ unsigned short lA[BM * CDIM];
    __shared__ unsigned short lW[CDIM * CDIM];

    #pragma unroll
    for (int i = 0; i < 8; ++i) {
        int flat = (i * 256 + tid) * 8;
        int row = flat >> 7, col = flat & 127;
        short8 v = *reinterpret_cast<const short8*>(W2t + flat);
        *reinterpret_cast<short8*>(&lW[swz(row, col)]) = v;
    }

    #pragma unroll
    for (int p = 0; p < 8; ++p) {
        int r = p * 16 + (tid >> 4);
        int c = (tid & 15) * 8;
        int m = mbase + r;
        short8 v = {0, 0, 0, 0, 0, 0, 0, 0};
        if (m < N) v = *reinterpret_cast<const short8*>(c1 + (size_t)m * CDIM + c);
        *reinterpret_cast<short8*>(&lA[swz(r, c)]) = v;
    }
    __syncthreads();

    const int wid  = tid >> 6, lane = tid & 63;
    const int wr   = (wid >> 1) * 64, wc = (wid & 1) * 64;
    const int lrow = lane & 15, quad = lane >> 4;

    f32x4 acc[4][4];
    #pragma unroll
    for (int i = 0; i < 4; ++i)
        #pragma unroll
        for (int j = 0; j < 4; ++j)
            acc[i][j] = {0.f, 0.f, 0.f, 0.f};

    #pragma unroll
    for (int s = 0; s < 4; ++s) {
        const int kf = s * 32 + quad * 8;
        short8 a[4], b[4];
        #pragma unroll
        for (int i = 0; i < 4; ++i)
            a[i] = *reinterpret_cast<const short8*>(&lA[swz(wr + i * 16 + lrow, kf)]);
        #pragma unroll
        for (int j = 0; j < 4; ++j)
            b[j] = *reinterpret_cast<const short8*>(&lW[swz(wc + j * 16 + lrow, kf)]);
        #pragma unroll
        for (int i = 0; i < 4; ++i)
            #pragma unroll
            for (int j = 0; j < 4; ++j)
                acc[i][j] = __builtin_amdgcn_mfma_f32_16x16x32_bf16(a[i], b[j], acc[i][j], 0, 0, 0);
    }

    #pragma unroll
    for (int i = 0; i < 4; ++i) {
        #pragma unroll
        for (int reg = 0; reg < 4; ++reg) {
            int m = mbase + wr + i * 16 + quad * 4 + reg;
            if (m < N) {
                unsigned short* dst = c2 + (size_t)m * CDIM + wc + lrow;
                #pragma unroll
                for (int j = 0; j < 4; ++j)
                    dst[j * 16] = f2bf(lrelu(acc[i][j][reg]));
            }
        }
    }
}

// ---------------------------------------------------------------- launch
extern "C" void kernel_launch(void* const* d_in, const int* in_sizes, int n_in,
                              void* d_out, int out_size, void* d_ws, size_t ws_size,
                              hipStream_t stream) {
    const float* feats   = (const float*)d_in[0];
    const float* W1      = (const float*)d_in[1];
    const float* W2      = (const float*)d_in[2];
    const float* W3      = (const float*)d_in[3];
    const int*   in_map  = (const int*)d_in[4];
    const int*   out_map = (const int*)d_in[5];
    const float* mask    = (const float*)d_in[6];
    float*       out     = (float*)d_out;

    const int K   = KTAPS;
    const int N   = in_sizes[0] / CDIM;           // 200000
    const int M   = in_sizes[4] / K;              // 100000
    const int NT  = (N + 127) >> 7;               // 1563 output tiles
    const int NB  = NT * K;                       // 42201 bins
    const int NBb = (NB + 255) >> 8;              // 165 scan blocks (<=256 req)
    const int CAP = K * M + 16 * NB;              // padded entry capacity

    // workspace layout (512B-aligned sub-buffers)
    char* w = (char*)d_ws;
    size_t o = 0;
    auto alloc = [&](size_t bytes) -> void* {
        void* p = w + o; o = (o + bytes + 511) & ~(size_t)511; return p;
    };
    unsigned short* Abf  = (unsigned short*)alloc((size_t)(N + 1) * CDIM * 2); // feats bf16; reused as c2
    unsigned short* W1t  = (unsigned short*)alloc((size_t)K * CDIM * CDIM * 2);
    unsigned short* W3t  = (unsigned short*)alloc((size_t)K * CDIM * CDIM * 2);
    unsigned short* W2t  = (unsigned short*)alloc((size_t)CDIM * CDIM * 2);
    int* cnt      = (int*)alloc((size_t)NB * 4);
    int* cursor   = (int*)alloc((size_t)NB * 4);
    int* cs       = (int*)alloc((size_t)(NB + 1) * 4);
    int* partials = (int*)alloc(256 * 4);
    int* pairs    = (int*)alloc((size_t)CAP * 4);
    if (o > ws_size) return;   // fail loudly rather than corrupt

    unsigned short* c1bf = (unsigned short*)d_out;   // c1 (bf16, lrelu'd) lives in d_out

    // convert inputs
    const int n4 = N * CDIM / 4;
    cvt_feats_kernel<<<(n4 + 255) / 256, 256, 0, stream>>>(feats, Abf, n4);
    hipMemsetAsync(Abf + (size_t)N * CDIM, 0, CDIM * 2, stream);  // zero row N (dummy target)
    const int wtot = 2 * K * CDIM * CDIM + CDIM * CDIM;
    cvt_weights_kernel<<<(wtot + 255) / 256, 256, 0, stream>>>(W1, W2, W3, W1t, W2t, W3t);

    // binning prep (shared by conv1 & conv3)
    hipMemsetAsync(cnt, 0, (size_t)NB * 4, stream);
    hipMemsetAsync(cursor, 0, (size_t)NB * 4, stream);
    dim3 gmap((M + 255) / 256, K);
    hist_kernel<<<gmap, 256, 0, stream>>>(out_map, cnt, M);
    scan_a_kernel<<<NBb, 256, 0, stream>>>(cnt, cs, partials, NB);
    scan_b_kernel<<<1, 256, 0, stream>>>(partials, NBb);
    scan_c_kernel<<<NBb, 256, 0, stream>>>(cs, partials, NB, NBb);
    const int DUMMY = (N << 8);                   // in_row=N (zero row), scat_row=0, k=0
    fill_kernel<<<(CAP + 255) / 256, 256, 0, stream>>>(pairs, CAP, DUMMY);
    scatter_kernel<<<gmap, 256, 0, stream>>>(in_map, out_map, cs, cursor, pairs, M);

    // conv1: feats -> c1 (bf16, lrelu'd, in d_out)
    conv_fused_kernel<0><<<NT, 1024, 0, stream>>>(Abf, W1t, pairs, cs, c1bf, nullptr, nullptr, N);
    // conv2: c1 @ W2 -> c2 (bf16, overwrites Abf; row N stays zero)
    conv2_kernel<<<NT, 256, 0, stream>>>(c1bf, W2t, Abf, N);
    // conv3: c2 -> out (fp32, *mask fused)
    conv_fused_kernel<1><<<NT, 1024, 0, stream>>>(Abf, W3t, pairs, cs, nullptr, out, mask, N);
}

// Round 4
// 4735.199 us; speedup vs baseline: 1.1774x; 1.1774x over previous
//
#include <hip/hip_runtime.h>
#include <hip/hip_bf16.h>

// SparseBottleneck, output-stationary v3: wave-autonomous chunks.
// v1/v2 were TCP/convoy-latency bound (every load a 16-cluster gather; v2
// added a block-wide barrier+vmcnt(0) per bin with ~1 task/wave). v3: no
// barriers in the hot loop; block = (128-row tile, 64-col half); each wave
// walks a contiguous chunk range holding its W half-tile in 64 VGPRs
// (L2-resident Wt, reloaded only on bin crossings); swapped-operand MFMA
// makes the LDS scatter lane-local (no shfl, consecutive ds_add addresses).

typedef __attribute__((ext_vector_type(8))) short short8;
typedef __attribute__((ext_vector_type(4))) float f32x4;

#define CDIM 128
#define BM   128
#define KTAPS 27
#define LST   65            // lacc stride (odd -> ds_add banks spread)
#define NEG_SLOPE 0.2f

__device__ __forceinline__ unsigned short f2bf(float x) {
    union { float f; unsigned u; } un; un.f = x;
    unsigned r = un.u + 0x7fffu + ((un.u >> 16) & 1u);   // RNE
    return (unsigned short)(r >> 16);
}

__device__ __forceinline__ float lrelu(float x) {
    return x >= 0.f ? x : NEG_SLOPE * x;
}

// swizzled LDS element index for conv2's staging (proven earlier)
__device__ __forceinline__ int swz(int r, int c) {
    return (r << 7) + ((((c >> 3) ^ (r & 15)) << 3));
}

// ---------------------------------------------------------------- converters
__global__ void cvt_feats_kernel(const float* __restrict__ in,
                                 unsigned short* __restrict__ out, int n4) {
    int i = blockIdx.x * blockDim.x + threadIdx.x;
    if (i >= n4) return;
    float4 v = reinterpret_cast<const float4*>(in)[i];
    ushort4 o;
    o.x = f2bf(v.x); o.y = f2bf(v.y); o.z = f2bf(v.z); o.w = f2bf(v.w);
    reinterpret_cast<ushort4*>(out)[i] = o;
}

// W1/W3: [K][Cin][Cout] -> Wt[K][Cout][Cin] bf16 (plain transpose, no swizzle
// -- v3 reads W straight into registers). W2: [Cin][Cout] -> W2t[Cout][Cin].
__global__ void cvt_weights_kernel(const float* __restrict__ W1,
                                   const float* __restrict__ W2,
                                   const float* __restrict__ W3,
                                   unsigned short* __restrict__ W1t,
                                   unsigned short* __restrict__ W2t,
                                   unsigned short* __restrict__ W3t) {
    const int KW = KTAPS * 128 * 128;                 // 442368
    int t = blockIdx.x * blockDim.x + threadIdx.x;
    if (t < KW) {
        int k = t >> 14, r = t & 16383, n = r >> 7, kk = r & 127;
        W1t[t] = f2bf(W1[(k << 14) + (kk << 7) + n]);
    } else if (t < 2 * KW) {
        int t2 = t - KW;
        int k = t2 >> 14, r = t2 & 16383, n = r >> 7, kk = r & 127;
        W3t[t2] = f2bf(W3[(k << 14) + (kk << 7) + n]);
    } else if (t < 2 * KW + 16384) {
        int t2 = t - 2 * KW;
        int n = t2 >> 7, kk = t2 & 127;
        W2t[t2] = f2bf(W2[(kk << 7) + n]);
    }
}

// ---------------------------------------------------------------- binning prep
// bin = (out_row >> 7) * 27 + k ; runs once, reused by conv1 AND conv3.
__global__ void hist_kernel(const int* __restrict__ out_map,
                            int* __restrict__ cnt, int M) {
    int m = blockIdx.x * 256 + threadIdx.x;
    if (m >= M) return;
    int k = blockIdx.y;
    int orow = out_map[(size_t)k * M + m];
    atomicAdd(cnt + ((orow >> 7) * KTAPS + k), 1);
}

__global__ void scan_a_kernel(const int* __restrict__ cnt, int* __restrict__ cs,
                              int* __restrict__ partials, int NB) {
    __shared__ int sd[256];
    int tid = threadIdx.x, bin = blockIdx.x * 256 + tid;
    int v = (bin < NB) ? ((cnt[bin] + 15) >> 4) : 0;
    sd[tid] = v; __syncthreads();
    for (int off = 1; off < 256; off <<= 1) {
        int t = (tid >= off) ? sd[tid - off] : 0; __syncthreads();
        sd[tid] += t; __syncthreads();
    }
    if (bin < NB) cs[bin] = sd[tid] - v;      // block-local exclusive
    if (tid == 255) partials[blockIdx.x] = sd[255];
}

__global__ void scan_b_kernel(int* __restrict__ partials, int NBb) {
    __shared__ int sd[256];
    int tid = threadIdx.x;
    int v = (tid < NBb) ? partials[tid] : 0;
    sd[tid] = v; __syncthreads();
    for (int off = 1; off < 256; off <<= 1) {
        int t = (tid >= off) ? sd[tid - off] : 0; __syncthreads();
        sd[tid] += t; __syncthreads();
    }
    partials[tid] = sd[tid] - v;              // exclusive; partials[NBb] = total
}

__global__ void scan_c_kernel(int* __restrict__ cs, const int* __restrict__ partials,
                              int NB, int NBb) {
    int bin = blockIdx.x * 256 + threadIdx.x;
    if (bin < NB) cs[bin] += partials[blockIdx.x];
    if (bin == 0) cs[NB] = partials[NBb];
}

__global__ void fill_kernel(int* __restrict__ p, int n, int v) {
    int i = blockIdx.x * 256 + threadIdx.x;
    if (i < n) p[i] = v;
}

// entry pack: (k<<26) | (in_row<<8) | (out_row & 127)
__global__ void scatter_kernel(const int* __restrict__ in_map,
                               const int* __restrict__ out_map,
                               const int* __restrict__ cs,
                               int* __restrict__ cursor,
                               int* __restrict__ pairs, int M) {
    int m = blockIdx.x * 256 + threadIdx.x;
    if (m >= M) return;
    int k = blockIdx.y;
    size_t e = (size_t)k * M + m;
    int orow = out_map[e], irow = in_map[e];
    int bin = (orow >> 7) * KTAPS + k;
    int pos = atomicAdd(cursor + bin, 1);
    pairs[(size_t)cs[bin] * 16 + pos] = (k << 26) | (irow << 8) | (orow & 127);
}

// ---------------------------------------------------------------- fused sconv
// Grid (NT, 2): block = (tile, col-half). 512 thr (8 waves), 2 blocks/CU.
// Wave walks a contiguous chunk range of the tile; W half (64 chans x 128)
// in registers, reloaded on bin crossings. Swapped MFMA: D[outchan][entry],
// lane's entry = lane&15 -> srow in-lane, ds_add addrs consecutive.
// Dummies: irow=N (zero row), srow=0 (adds exact 0.0f).
template<int MODE>
__global__ __launch_bounds__(512, 4)
void conv_fused_kernel(const unsigned short* __restrict__ A,    // [N+1,128] bf16, row N = 0
                       const unsigned short* __restrict__ Wt,   // [27][128][128] bf16 [k][n][kk]
                       const int* __restrict__ pairs,
                       const int* __restrict__ cs,              // [NB+1] chunk starts
                       unsigned short* __restrict__ bf_out,     // MODE 0
                       float* __restrict__ f_out,               // MODE 1
                       const float* __restrict__ mask,
                       int N) {
    __shared__ float lacc[128 * LST];                            // 32.5 KB
    __shared__ int lcs[KTAPS + 1];

    const int tid   = threadIdx.x;
    const int tile  = blockIdx.x;
    const int hhalf = blockIdx.y;                                // 0 / 1 col-half
    const int wid   = tid >> 6, lane = tid & 63;
    const int lrow  = lane & 15, quad = lane >> 4;

    for (int i = tid; i < 128 * LST; i += 512) lacc[i] = 0.f;
    if (tid <= KTAPS) lcs[tid] = cs[tile * KTAPS + tid];
    __syncthreads();

    const int lo = lcs[0], hi = lcs[KTAPS];
    const int total = hi - lo;
    const int per = (total + 7) >> 3;
    int c0 = lo + wid * per;
    int c1 = (c0 + per < hi) ? (c0 + per) : hi;

    if (c0 < c1) {
        int bin = 0;
        while (lcs[bin + 1] <= c0) ++bin;
        int nextb = lcs[bin + 1];

        short8 wf[4][4];                                         // 64 VGPR
        const unsigned short* wbase = Wt + ((size_t)bin << 14)
                                         + (((hhalf << 6) + lrow) << 7) + quad * 8;
        #pragma unroll
        for (int j = 0; j < 4; ++j)
            #pragma unroll
            for (int s = 0; s < 4; ++s)
                wf[j][s] = *reinterpret_cast<const short8*>(wbase + j * 2048 + s * 32);

        int pk = pairs[(size_t)c0 * 16 + lrow];                  // prologue pairs

        for (int c = c0; c < c1; ++c) {
            // bin advance (W reload; ~2-3 times per wave-range)
            if (c >= nextb) {
                do { ++bin; nextb = lcs[bin + 1]; } while (c >= nextb);
                const unsigned short* wb = Wt + ((size_t)bin << 14)
                                             + (((hhalf << 6) + lrow) << 7) + quad * 8;
                #pragma unroll
                for (int j = 0; j < 4; ++j)
                    #pragma unroll
                    for (int s = 0; s < 4; ++s)
                        wf[j][s] = *reinterpret_cast<const short8*>(wb + j * 2048 + s * 32);
            }

            int irow = (pk >> 8) & 0x3FFFF;
            int srow = pk & 127;
            const unsigned short* ar = A + ((size_t)irow << 7) + quad * 8;
            short8 a0 = *reinterpret_cast<const short8*>(ar);
            short8 a1 = *reinterpret_cast<const short8*>(ar + 32);
            short8 a2 = *reinterpret_cast<const short8*>(ar + 64);
            short8 a3 = *reinterpret_cast<const short8*>(ar + 96);

            if (c + 1 < c1) pk = pairs[(size_t)(c + 1) * 16 + lrow];  // prefetch

            const int ad0 = srow * LST + quad * 4;
            #pragma unroll
            for (int j = 0; j < 4; ++j) {
                f32x4 acc = {0.f, 0.f, 0.f, 0.f};
                acc = __builtin_amdgcn_mfma_f32_16x16x32_bf16(wf[j][0], a0, acc, 0, 0, 0);
                acc = __builtin_amdgcn_mfma_f32_16x16x32_bf16(wf[j][1], a1, acc, 0, 0, 0);
                acc = __builtin_amdgcn_mfma_f32_16x16x32_bf16(wf[j][2], a2, acc, 0, 0, 0);
                acc = __builtin_amdgcn_mfma_f32_16x16x32_bf16(wf[j][3], a3, acc, 0, 0, 0);
                // D[outchan = j*16 + quad*4 + reg][entry = lrow]; srow is lane-local
                #pragma unroll
                for (int r = 0; r < 4; ++r)
                    __hip_atomic_fetch_add(&lacc[ad0 + j * 16 + r], acc[r],
                                           __ATOMIC_RELAXED, __HIP_MEMORY_SCOPE_WORKGROUP);
            }
        }
    }
    __syncthreads();

    // epilogue: block writes cols [hhalf*64, +64) of its 128 rows, once each
    const int gbase = tile << 7;
    if (MODE == 0) {
        for (int i = tid; i < 128 * 32; i += 512) {              // ushort2 units
            int r = i >> 5, cp = i & 31;
            int g = gbase + r;
            if (g < N) {
                float v0 = lacc[r * LST + cp * 2];
                float v1 = lacc[r * LST + cp * 2 + 1];
                ushort2 o = { f2bf(lrelu(v0)), f2bf(lrelu(v1)) };
                *reinterpret_cast<ushort2*>(bf_out + (size_t)g * CDIM + (hhalf << 6) + cp * 2) = o;
            }
        }
    } else {
        for (int i = tid; i < 128 * 32; i += 512) {              // float2 units
            int r = i >> 5, cp = i & 31;
            int g = gbase + r;
            if (g < N) {
                float mv = mask[g];
                float2 o = { lacc[r * LST + cp * 2] * mv,
                             lacc[r * LST + cp * 2 + 1] * mv };
                *reinterpret_cast<float2*>(f_out + (size_t)g * CDIM + (hhalf << 6) + cp * 2) = o;
            }
        }
    }
}

// ---------------------------------------------------------------- dense conv2
// c2 = bf16(lrelu( c1 @ W2 ))  -- c1 already lrelu'd bf16 (written by conv1)
__global__ __launch_bounds__(256, 2)
void conv2_kernel(const unsigned short* __restrict__ c1,      // [N,128] bf16
                  const unsigned short* __restrict__ W2t,     // [128,128] bf16 [n][kk]
                  unsigned short* __restrict__ c2,            // [N,128] bf16
                  int N) {
    const int mbase = blockIdx.x * BM;
    const int tid   = threadIdx.x;

    __shared__ unsigned short lA[BM * CDIM];
    __shared__ unsigned short lW[CDIM * CDIM];

    #pragma unroll
    for (int i = 0; i < 8; ++i) {
        int flat = (i * 256 + tid) * 8;
        int row = flat >> 7, col = flat & 127;
        short8 v = *reinterpret_cast<const short8*>(W2t + flat);
        *reinterpret_cast<short8*>(&lW[swz(row, col)]) = v;
    }

    #pragma unroll
    for (int p = 0; p < 8; ++p) {
        int r = p * 16 + (tid >> 4);
        int c = (tid & 15) * 8;
        int m = mbase + r;
        short8 v = {0, 0, 0, 0, 0, 0, 0, 0};
        if (m < N) v = *reinterpret_cast<const short8*>(c1 + (size_t)m * CDIM + c);
        *reinterpret_cast<short8*>(&lA[swz(r, c)]) = v;
    }
    __syncthreads();

    const int wid  = tid >> 6, lane = tid & 63;
    const int wr   = (wid >> 1) * 64, wc = (wid & 1) * 64;
    const int lrow = lane & 15, quad = lane >> 4;

    f32x4 acc[4][4];
    #pragma unroll
    for (int i = 0; i < 4; ++i)
        #pragma unroll
        for (int j = 0; j < 4; ++j)
            acc[i][j] = {0.f, 0.f, 0.f, 0.f};

    #pragma unroll
    for (int s = 0; s < 4; ++s) {
        const int kf = s * 32 + quad * 8;
        short8 a[4], b[4];
        #pragma unroll
        for (int i = 0; i < 4; ++i)
            a[i] = *reinterpret_cast<const short8*>(&lA[swz(wr + i * 16 + lrow, kf)]);
        #pragma unroll
        for (int j = 0; j < 4; ++j)
            b[j] = *reinterpret_cast<const short8*>(&lW[swz(wc + j * 16 + lrow, kf)]);
        #pragma unroll
        for (int i = 0; i < 4; ++i)
            #pragma unroll
            for (int j = 0; j < 4; ++j)
                acc[i][j] = __builtin_amdgcn_mfma_f32_16x16x32_bf16(a[i], b[j], acc[i][j], 0, 0, 0);
    }

    #pragma unroll
    for (int i = 0; i < 4; ++i) {
        #pragma unroll
        for (int reg = 0; reg < 4; ++reg) {
            int m = mbase + wr + i * 16 + quad * 4 + reg;
            if (m < N) {
                unsigned short* dst = c2 + (size_t)m * CDIM + wc + lrow;
                #pragma unroll
                for (int j = 0; j < 4; ++j)
                    dst[j * 16] = f2bf(lrelu(acc[i][j][reg]));
            }
        }
    }
}

// ---------------------------------------------------------------- launch
extern "C" void kernel_launch(void* const* d_in, const int* in_sizes, int n_in,
                              void* d_out, int out_size, void* d_ws, size_t ws_size,
                              hipStream_t stream) {
    const float* feats   = (const float*)d_in[0];
    const float* W1      = (const float*)d_in[1];
    const float* W2      = (const float*)d_in[2];
    const float* W3      = (const float*)d_in[3];
    const int*   in_map  = (const int*)d_in[4];
    const int*   out_map = (const int*)d_in[5];
    const float* mask    = (const float*)d_in[6];
    float*       out     = (float*)d_out;

    const int K   = KTAPS;
    const int N   = in_sizes[0] / CDIM;           // 200000
    const int M   = in_sizes[4] / K;              // 100000
    const int NT  = (N + 127) >> 7;               // 1563 output tiles
    const int NB  = NT * K;                       // 42201 bins
    const int NBb = (NB + 255) >> 8;              // 165 scan blocks (<=256 req)
    const int CAP = K * M + 16 * NB + 16;         // padded entry capacity

    // workspace layout (512B-aligned sub-buffers)
    char* w = (char*)d_ws;
    size_t o = 0;
    auto alloc = [&](size_t bytes) -> void* {
        void* p = w + o; o = (o + bytes + 511) & ~(size_t)511; return p;
    };
    unsigned short* Abf  = (unsigned short*)alloc((size_t)(N + 1) * CDIM * 2); // feats bf16; reused as c2
    unsigned short* W1t  = (unsigned short*)alloc((size_t)K * CDIM * CDIM * 2);
    unsigned short* W3t  = (unsigned short*)alloc((size_t)K * CDIM * CDIM * 2);
    unsigned short* W2t  = (unsigned short*)alloc((size_t)CDIM * CDIM * 2);
    int* cnt      = (int*)alloc((size_t)NB * 4);
    int* cursor   = (int*)alloc((size_t)NB * 4);
    int* cs       = (int*)alloc((size_t)(NB + 1) * 4);
    int* partials = (int*)alloc(256 * 4);
    int* pairs    = (int*)alloc((size_t)CAP * 4);
    if (o > ws_size) return;   // fail loudly rather than corrupt

    unsigned short* c1bf = (unsigned short*)d_out;   // c1 (bf16, lrelu'd) lives in d_out

    // convert inputs
    const int n4 = N * CDIM / 4;
    cvt_feats_kernel<<<(n4 + 255) / 256, 256, 0, stream>>>(feats, Abf, n4);
    hipMemsetAsync(Abf + (size_t)N * CDIM, 0, CDIM * 2, stream);  // zero row N (dummy target)
    const int wtot = 2 * K * CDIM * CDIM + CDIM * CDIM;
    cvt_weights_kernel<<<(wtot + 255) / 256, 256, 0, stream>>>(W1, W2, W3, W1t, W2t, W3t);

    // binning prep (shared by conv1 & conv3)
    hipMemsetAsync(cnt, 0, (size_t)NB * 4, stream);
    hipMemsetAsync(cursor, 0, (size_t)NB * 4, stream);
    dim3 gmap((M + 255) / 256, K);
    hist_kernel<<<gmap, 256, 0, stream>>>(out_map, cnt, M);
    scan_a_kernel<<<NBb, 256, 0, stream>>>(cnt, cs, partials, NB);
    scan_b_kernel<<<1, 256, 0, stream>>>(partials, NBb);
    scan_c_kernel<<<NBb, 256, 0, stream>>>(cs, partials, NB, NBb);
    const int DUMMY = (N << 8);                   // in_row=N (zero row), scat_row=0, k=0
    fill_kernel<<<(CAP + 255) / 256, 256, 0, stream>>>(pairs, CAP, DUMMY);
    scatter_kernel<<<gmap, 256, 0, stream>>>(in_map, out_map, cs, cursor, pairs, M);

    dim3 gconv(NT, 2);
    // conv1: feats -> c1 (bf16, lrelu'd, in d_out)
    conv_fused_kernel<0><<<gconv, 512, 0, stream>>>(Abf, W1t, pairs, cs, c1bf, nullptr, nullptr, N);
    // conv2: c1 @ W2 -> c2 (bf16, overwrites Abf; row N stays zero)
    conv2_kernel<<<NT, 256, 0, stream>>>(c1bf, W2t, Abf, N);
    // conv3: c2 -> out (fp32, *mask fused)
    conv_fused_kernel<1><<<gconv, 512, 0, stream>>>(Abf, W3t, pairs, cs, nullptr, out, mask, N);
}